// Round 21
// baseline (84.467 us; speedup 1.0000x reference)
//
#include <hip/hip_runtime.h>

namespace {

constexpr int Tt = 32;    // frames (t)
constexpr int Ss = 784;   // floats per row (h*w)

using bf16x8 = __attribute__((ext_vector_type(8))) short;
using f32x4  = __attribute__((ext_vector_type(4))) float;

// split fp32 -> hi (truncated bf16) + lo (bf16 of residual); pack 2 per uint
__device__ inline void cvt2(float a, float b, unsigned& h, unsigned& l) {
  const unsigned ha = __float_as_uint(a) >> 16;
  const unsigned hb = __float_as_uint(b) >> 16;
  const float ra = a - __uint_as_float(ha << 16);
  const float rb = b - __uint_as_float(hb << 16);
  const unsigned la = __float_as_uint(ra) >> 16;
  const unsigned lb = __float_as_uint(rb) >> 16;
  h = ha | (hb << 16);
  l = la | (lb << 16);
}

// async global->LDS, 16 B per lane; LDS dest must be wave-uniform base.
__device__ inline void gload16(const float* g, float* l) {
  __builtin_amdgcn_global_load_lds(
      (const __attribute__((address_space(1))) void*)g,
      (__attribute__((address_space(3))) void*)l, 16, 0, 0);
}

// ---------------------------------------------------------------------------
// Kernel 1: per-(b,c) Gram via split-bf16 MFMA, direct-global fragments
// (unchanged from rounds 10-20; measured ~15-16 us = its HBM floor).
// ---------------------------------------------------------------------------
__global__ __launch_bounds__(256, 4) void gram_partial(const float* __restrict__ x,
                                                       float* __restrict__ part) {
  const int bc = blockIdx.x;                       // b*64 + c
  const float* __restrict__ xb = x + (size_t)bc * (Tt * Ss);
  const int tid  = threadIdx.x;
  const int w    = tid >> 6;          // wave 0..3
  const int lane = tid & 63;
  const int col  = lane & 15;
  const int g    = lane >> 4;

  f32x4 d1[2][2], d2[2][2], d3[2][2];
#pragma unroll
  for (int i = 0; i < 2; ++i)
#pragma unroll
    for (int j = 0; j < 2; ++j) { d1[i][j] = 0.f; d2[i][j] = 0.f; d3[i][j] = 0.f; }

  const float* __restrict__ pa = xb + (size_t)col * Ss;         // rows 0-15
  const float* __restrict__ pb = xb + (size_t)(16 + col) * Ss;  // rows 16-31

  for (int ks = w; ks < 25; ks += 4) {
    const int s0 = ks * 32 + g * 8;
    uint4 ha = {0u,0u,0u,0u}, la = {0u,0u,0u,0u};
    uint4 hb = {0u,0u,0u,0u}, lb = {0u,0u,0u,0u};
    if (s0 < 784) {
      const float4 a0 = *reinterpret_cast<const float4*>(pa + s0);
      const float4 a1 = *reinterpret_cast<const float4*>(pa + s0 + 4);
      const float4 b0 = *reinterpret_cast<const float4*>(pb + s0);
      const float4 b1 = *reinterpret_cast<const float4*>(pb + s0 + 4);
      cvt2(a0.x, a0.y, ha.x, la.x);
      cvt2(a0.z, a0.w, ha.y, la.y);
      cvt2(a1.x, a1.y, ha.z, la.z);
      cvt2(a1.z, a1.w, ha.w, la.w);
      cvt2(b0.x, b0.y, hb.x, lb.x);
      cvt2(b0.z, b0.w, hb.y, lb.y);
      cvt2(b1.x, b1.y, hb.z, lb.z);
      cvt2(b1.z, b1.w, hb.w, lb.w);
    }
    const bf16x8 h0 = __builtin_bit_cast(bf16x8, ha);
    const bf16x8 l0 = __builtin_bit_cast(bf16x8, la);
    const bf16x8 h1 = __builtin_bit_cast(bf16x8, hb);
    const bf16x8 l1 = __builtin_bit_cast(bf16x8, lb);
    d1[0][0] = __builtin_amdgcn_mfma_f32_16x16x32_bf16(h0, h0, d1[0][0], 0, 0, 0);
    d1[0][1] = __builtin_amdgcn_mfma_f32_16x16x32_bf16(h0, h1, d1[0][1], 0, 0, 0);
    d1[1][0] = __builtin_amdgcn_mfma_f32_16x16x32_bf16(h1, h0, d1[1][0], 0, 0, 0);
    d1[1][1] = __builtin_amdgcn_mfma_f32_16x16x32_bf16(h1, h1, d1[1][1], 0, 0, 0);
    d2[0][0] = __builtin_amdgcn_mfma_f32_16x16x32_bf16(h0, l0, d2[0][0], 0, 0, 0);
    d2[0][1] = __builtin_amdgcn_mfma_f32_16x16x32_bf16(h0, l1, d2[0][1], 0, 0, 0);
    d2[1][0] = __builtin_amdgcn_mfma_f32_16x16x32_bf16(h1, l0, d2[1][0], 0, 0, 0);
    d2[1][1] = __builtin_amdgcn_mfma_f32_16x16x32_bf16(h1, l1, d2[1][1], 0, 0, 0);
    d3[0][0] = __builtin_amdgcn_mfma_f32_16x16x32_bf16(l0, h0, d3[0][0], 0, 0, 0);
    d3[0][1] = __builtin_amdgcn_mfma_f32_16x16x32_bf16(l0, h1, d3[0][1], 0, 0, 0);
    d3[1][0] = __builtin_amdgcn_mfma_f32_16x16x32_bf16(l1, h0, d3[1][0], 0, 0, 0);
    d3[1][1] = __builtin_amdgcn_mfma_f32_16x16x32_bf16(l1, h1, d3[1][1], 0, 0, 0);
  }

  // ---- epilogue: combine D1+D2+D3, reduce over 4 waves (LDS, 1 barrier) ----
  __shared__ float mtmp[4 * 1056];    // 16896 B
#pragma unroll
  for (int i = 0; i < 2; ++i)
#pragma unroll
    for (int j = 0; j < 2; ++j) {
      const f32x4 s4 = d1[i][j] + d2[i][j] + d3[i][j];
#pragma unroll
      for (int r = 0; r < 4; ++r) {
        const int row = i * 16 + g * 4 + r;       // m89-verified C/D map
        const int cc  = j * 16 + col;
        mtmp[w * 1056 + row * 33 + cc] = s4[r];
      }
    }
  __syncthreads();

  const int e0 = tid * 4;
  float tmp[4];
#pragma unroll
  for (int u = 0; u < 4; ++u) {
    const int row = (e0 + u) >> 5;
    const int cc  = (e0 + u) & 31;
    float ss = 0.f;
#pragma unroll
    for (int ww = 0; ww < 4; ++ww) ss += mtmp[ww * 1056 + row * 33 + cc];
    tmp[u] = ss;
  }
  float4 o4;
  o4.x = tmp[0]; o4.y = tmp[1]; o4.z = tmp[2]; o4.w = tmp[3];
  *reinterpret_cast<float4*>(part + (size_t)bc * 1024 + e0) = o4;
}

// ---------------------------------------------------------------------------
// Kernel 2: reduce partials over c.  msum[b][e] = sum_c part[b*64+c][e]
// ---------------------------------------------------------------------------
__global__ __launch_bounds__(256) void reduce_c(const float* __restrict__ part,
                                                float* __restrict__ msum) {
  const int bid = blockIdx.x;                // 0..63
  const int b   = bid >> 2;
  const int e   = (bid & 3) * 256 + threadIdx.x;   // 0..1023
  const float* __restrict__ p = part + (size_t)b * 64 * 1024 + e;
  float s0 = 0.f, s1 = 0.f, s2 = 0.f, s3 = 0.f;
#pragma unroll
  for (int c = 0; c < 64; c += 4) {
    s0 += p[(size_t)(c + 0) * 1024];
    s1 += p[(size_t)(c + 1) * 1024];
    s2 += p[(size_t)(c + 2) * 1024];
    s3 += p[(size_t)(c + 3) * 1024];
  }
  msum[b * 1024 + e] = (s0 + s1) + (s2 + s3);
}

// ---------------------------------------------------------------------------
// Kernel 3: softmax over the BATCH axis. Output q-major: mq[b][q*32+k].
// ---------------------------------------------------------------------------
__global__ __launch_bounds__(256) void softmax_b(const float* __restrict__ msum,
                                                 float* __restrict__ mq) {
  const int e = blockIdx.x * 256 + threadIdx.x;    // q*32 + k
  float l[16];
  float mx = -3.4e38f;
#pragma unroll
  for (int b = 0; b < 16; ++b) {
    l[b] = msum[b * 1024 + e];
    mx = fmaxf(mx, l[b]);
  }
  float s = 0.f;
#pragma unroll
  for (int b = 0; b < 16; ++b) {
    l[b] = expf(l[b] - mx);
    s += l[b];
  }
  const float inv = 1.f / s;
#pragma unroll
  for (int b = 0; b < 16; ++b) mq[b * 1024 + e] = l[b] * inv;
}

// ---------------------------------------------------------------------------
// Kernel 4: PV — WAVE-PRIVATE PIPELINES, ZERO BARRIERS.
// Theory: every prior pv (57-62 us across all other axes) rendezvouses all
// waves at s_barriers; the 6.3 TB/s copy kernel has none. Here each of 8
// waves owns frags {w, w+8, ..., w+40} with a private 3-deep 2 KB LDS ring,
// private counted vmcnt (2 loads + 2 stores per iter, depth 3 ->
// N = {4,6,8,8,6,4}), and NO s_barrier / __syncthreads anywhere.
// 1024 blocks x 512 threads (8 waves); LDS 8*3*2048 = 49152 B -> 3 blocks/CU
// = 24 independent wave-pipelines per CU. Frag math / C->D store map
// byte-identical to r18-r20 (validated, absmax 0.0625). Frag 48 (s 768..783)
// handled direct-global by wave 0. __launch_bounds__(512,4): VGPR cap 128.
// ---------------------------------------------------------------------------
__global__ __launch_bounds__(512, 4) void pv(const float* __restrict__ xv,
                                             const float* __restrict__ mq,
                                             float* __restrict__ out) {
  const int bc = blockIdx.x;                  // b*64 + c
  const int b  = bc >> 6;
  const float* __restrict__ xvb = xv + (size_t)bc * (Tt * Ss);
  float* __restrict__ ob        = out + (size_t)bc * (Tt * Ss);

  const int tid  = threadIdx.x;
  const int w    = tid >> 6;                  // wave 0..7
  const int lane = tid & 63;
  const int col  = lane & 15;                 // frag column / M row
  const int g    = lane >> 4;                 // k-group (k = 8g..8g+7)

  __shared__ float lds[8 * 3 * 512];          // 8 waves x 3 bufs x 2 KB
  float* __restrict__ wbase = &lds[w * 3 * 512];

  // ---- M fragments (once per wave; no barrier needed) — r9/r16-validated --
  bf16x8 mh[2], ml[2];
#pragma unroll
  for (int qf = 0; qf < 2; ++qf) {
    const float* mp = mq + b * 1024 + (qf * 16 + col) * 32 + g * 8;
    const float4 ma = *reinterpret_cast<const float4*>(mp);
    const float4 mb = *reinterpret_cast<const float4*>(mp + 4);
    uint4 h, l;
    cvt2(ma.x, ma.y, h.x, l.x);
    cvt2(ma.z, ma.w, h.y, l.y);
    cvt2(mb.x, mb.y, h.z, l.z);
    cvt2(mb.z, mb.w, h.w, l.w);
    mh[qf] = __builtin_bit_cast(bf16x8, h);
    ml[qf] = __builtin_bit_cast(bf16x8, l);
  }

  // stage frag sf into ring slot t: 2 x gload16 (1 KB each = 16 rows).
  // LDS float layout: slot t, row r (=p*16 + lane>>2), float offset
  // t*512 + r*16 + (lane&3)*4  (== lane*4 auto-offset per instr). Wave-local.
  auto stage = [&](int t, int sf) {
#pragma unroll
    for (int p = 0; p < 2; ++p) {
      const int row = p * 16 + (lane >> 2);
      gload16(xvb + (size_t)row * Ss + sf * 16 + (lane & 3) * 4,
              wbase + t * 512 + p * 256);
    }
  };

  // compute frag sf from ring slot t: 8 ds_read, cvt, 6 MFMA, 2 float4 stores
  auto frag = [&](int t, int sf) {
    float f8[8];
#pragma unroll
    for (int j = 0; j < 8; ++j)
      f8[j] = wbase[t * 512 + (8 * g + j) * 16 + col];
    uint4 hh, lv;
    cvt2(f8[0], f8[1], hh.x, lv.x);
    cvt2(f8[2], f8[3], hh.y, lv.y);
    cvt2(f8[4], f8[5], hh.z, lv.z);
    cvt2(f8[6], f8[7], hh.w, lv.w);
    const bf16x8 vh = __builtin_bit_cast(bf16x8, hh);
    const bf16x8 vl = __builtin_bit_cast(bf16x8, lv);
    const int s0 = sf * 16;
#pragma unroll
    for (int qf = 0; qf < 2; ++qf) {
      f32x4 d = {0.f, 0.f, 0.f, 0.f};
      d = __builtin_amdgcn_mfma_f32_16x16x32_bf16(vl, mh[qf], d, 0, 0, 0);
      d = __builtin_amdgcn_mfma_f32_16x16x32_bf16(vh, ml[qf], d, 0, 0, 0);
      d = __builtin_amdgcn_mfma_f32_16x16x32_bf16(vh, mh[qf], d, 0, 0, 0);
      // D[s][q]: lane(col,g) regs = s0+4g..+3 of q-row qf*16+col (r18-valid)
      float4 o4;
      o4.x = d[0]; o4.y = d[1]; o4.z = d[2]; o4.w = d[3];
      *reinterpret_cast<float4*>(ob + (size_t)(qf * 16 + col) * Ss + s0 + 4 * g) = o4;
    }
  };

  // prologue: 3-deep prefetch of this wave's first three frags
  stage(0, w);
  stage(1, w + 8);
  stage(2, w + 16);

#pragma unroll
  for (int i = 0; i < 6; ++i) {
    // counted wait: frag f(i)'s 2 loads complete; newer loads/stores in flight
    if (i == 0)      asm volatile("s_waitcnt vmcnt(4)" ::: "memory");
    else if (i == 1) asm volatile("s_waitcnt vmcnt(6)" ::: "memory");
    else if (i == 2) asm volatile("s_waitcnt vmcnt(8)" ::: "memory");
    else if (i == 3) asm volatile("s_waitcnt vmcnt(8)" ::: "memory");
    else if (i == 4) asm volatile("s_waitcnt vmcnt(6)" ::: "memory");
    else             asm volatile("s_waitcnt vmcnt(4)" ::: "memory");
    __builtin_amdgcn_sched_barrier(0);

    frag(i % 3, w + 8 * i);

    if (i + 3 < 6) {
      asm volatile("s_waitcnt lgkmcnt(0)" ::: "memory");  // ring slot reads done
      __builtin_amdgcn_sched_barrier(0);
      stage(i % 3, w + 8 * (i + 3));
    }
  }

  // ---- frag 48: s = 768..783, direct from global (wave 0 only) ----
  if (w == 0) {
    float f8[8];
#pragma unroll
    for (int j = 0; j < 8; ++j)
      f8[j] = xvb[(size_t)(8 * g + j) * Ss + 768 + col];
    uint4 hh, lv;
    cvt2(f8[0], f8[1], hh.x, lv.x);
    cvt2(f8[2], f8[3], hh.y, lv.y);
    cvt2(f8[4], f8[5], hh.z, lv.z);
    cvt2(f8[6], f8[7], hh.w, lv.w);
    const bf16x8 vh = __builtin_bit_cast(bf16x8, hh);
    const bf16x8 vl = __builtin_bit_cast(bf16x8, lv);
#pragma unroll
    for (int qf = 0; qf < 2; ++qf) {
      f32x4 d = {0.f, 0.f, 0.f, 0.f};
      d = __builtin_amdgcn_mfma_f32_16x16x32_bf16(vl, mh[qf], d, 0, 0, 0);
      d = __builtin_amdgcn_mfma_f32_16x16x32_bf16(vh, ml[qf], d, 0, 0, 0);
      d = __builtin_amdgcn_mfma_f32_16x16x32_bf16(vh, mh[qf], d, 0, 0, 0);
      float4 o4;
      o4.x = d[0]; o4.y = d[1]; o4.z = d[2]; o4.w = d[3];
      *reinterpret_cast<float4*>(ob + (size_t)(qf * 16 + col) * Ss + 768 + 4 * g) = o4;
    }
  }
}

}  // namespace

extern "C" void kernel_launch(void* const* d_in, const int* in_sizes, int n_in,
                              void* d_out, int out_size, void* d_ws, size_t ws_size,
                              hipStream_t stream) {
  const float* x  = (const float*)d_in[0];
  const float* xv = (const float*)d_in[1];
  float* out = (float*)d_out;

  // workspace (fp32), ~4.2 MiB total:
  float* part = (float*)d_ws;            // 1024 x 1024
  float* msum = part + 1024 * 1024;      // 16 x 1024
  float* mq   = msum + 16 * 1024;        // 16 x 1024 (q-major softmax weights)

  gram_partial<<<dim3(1024), dim3(256), 0, stream>>>(x, part);
  reduce_c<<<dim3(64), dim3(256), 0, stream>>>(part, msum);
  softmax_b<<<dim3(4), dim3(256), 0, stream>>>(msum, mq);
  pv<<<dim3(1024), dim3(512), 0, stream>>>(xv, mq, out);
}

// Round 23
// 78.834 us; speedup vs baseline: 1.0715x; 1.0715x over previous
//
#include <hip/hip_runtime.h>

namespace {

constexpr int Tt = 32;    // frames (t)
constexpr int Ss = 784;   // floats per row (h*w)

using bf16x8 = __attribute__((ext_vector_type(8))) short;
using f32x4  = __attribute__((ext_vector_type(4))) float;

// split fp32 -> hi (truncated bf16) + lo (bf16 of residual); pack 2 per uint
__device__ inline void cvt2(float a, float b, unsigned& h, unsigned& l) {
  const unsigned ha = __float_as_uint(a) >> 16;
  const unsigned hb = __float_as_uint(b) >> 16;
  const float ra = a - __uint_as_float(ha << 16);
  const float rb = b - __uint_as_float(hb << 16);
  const unsigned la = __float_as_uint(ra) >> 16;
  const unsigned lb = __float_as_uint(rb) >> 16;
  h = ha | (hb << 16);
  l = la | (lb << 16);
}

// async global->LDS, 16 B per lane; LDS dest must be wave-uniform base.
__device__ inline void gload16(const float* g, float* l) {
  __builtin_amdgcn_global_load_lds(
      (const __attribute__((address_space(1))) void*)g,
      (__attribute__((address_space(3))) void*)l, 16, 0, 0);
}

// same, with nt/slc cache policy (streaming read: don't keep in cache).
__device__ inline void gload16_nt(const float* g, float* l) {
  __builtin_amdgcn_global_load_lds(
      (const __attribute__((address_space(1))) void*)g,
      (__attribute__((address_space(3))) void*)l, 16, 0, 2 /*nt*/);
}

// non-temporal float4 store via native ext-vector type (HIP float4 class is
// rejected by the builtin; f32x4 is a vector-of-float and is accepted).
__device__ inline void ntstore4(f32x4 v, float* p) {
  __builtin_nontemporal_store(v, reinterpret_cast<f32x4*>(p));
}

// ---------------------------------------------------------------------------
// Kernel 1: per-(b,c) Gram via split-bf16 MFMA, direct-global fragments
// (unchanged from rounds 10-21; measured ~15-16 us = its HBM floor).
// ---------------------------------------------------------------------------
__global__ __launch_bounds__(256, 4) void gram_partial(const float* __restrict__ x,
                                                       float* __restrict__ part) {
  const int bc = blockIdx.x;                       // b*64 + c
  const float* __restrict__ xb = x + (size_t)bc * (Tt * Ss);
  const int tid  = threadIdx.x;
  const int w    = tid >> 6;          // wave 0..3
  const int lane = tid & 63;
  const int col  = lane & 15;
  const int g    = lane >> 4;

  f32x4 d1[2][2], d2[2][2], d3[2][2];
#pragma unroll
  for (int i = 0; i < 2; ++i)
#pragma unroll
    for (int j = 0; j < 2; ++j) { d1[i][j] = 0.f; d2[i][j] = 0.f; d3[i][j] = 0.f; }

  const float* __restrict__ pa = xb + (size_t)col * Ss;         // rows 0-15
  const float* __restrict__ pb = xb + (size_t)(16 + col) * Ss;  // rows 16-31

  for (int ks = w; ks < 25; ks += 4) {
    const int s0 = ks * 32 + g * 8;
    uint4 ha = {0u,0u,0u,0u}, la = {0u,0u,0u,0u};
    uint4 hb = {0u,0u,0u,0u}, lb = {0u,0u,0u,0u};
    if (s0 < 784) {
      const float4 a0 = *reinterpret_cast<const float4*>(pa + s0);
      const float4 a1 = *reinterpret_cast<const float4*>(pa + s0 + 4);
      const float4 b0 = *reinterpret_cast<const float4*>(pb + s0);
      const float4 b1 = *reinterpret_cast<const float4*>(pb + s0 + 4);
      cvt2(a0.x, a0.y, ha.x, la.x);
      cvt2(a0.z, a0.w, ha.y, la.y);
      cvt2(a1.x, a1.y, ha.z, la.z);
      cvt2(a1.z, a1.w, ha.w, la.w);
      cvt2(b0.x, b0.y, hb.x, lb.x);
      cvt2(b0.z, b0.w, hb.y, lb.y);
      cvt2(b1.x, b1.y, hb.z, lb.z);
      cvt2(b1.z, b1.w, hb.w, lb.w);
    }
    const bf16x8 h0 = __builtin_bit_cast(bf16x8, ha);
    const bf16x8 l0 = __builtin_bit_cast(bf16x8, la);
    const bf16x8 h1 = __builtin_bit_cast(bf16x8, hb);
    const bf16x8 l1 = __builtin_bit_cast(bf16x8, lb);
    d1[0][0] = __builtin_amdgcn_mfma_f32_16x16x32_bf16(h0, h0, d1[0][0], 0, 0, 0);
    d1[0][1] = __builtin_amdgcn_mfma_f32_16x16x32_bf16(h0, h1, d1[0][1], 0, 0, 0);
    d1[1][0] = __builtin_amdgcn_mfma_f32_16x16x32_bf16(h1, h0, d1[1][0], 0, 0, 0);
    d1[1][1] = __builtin_amdgcn_mfma_f32_16x16x32_bf16(h1, h1, d1[1][1], 0, 0, 0);
    d2[0][0] = __builtin_amdgcn_mfma_f32_16x16x32_bf16(h0, l0, d2[0][0], 0, 0, 0);
    d2[0][1] = __builtin_amdgcn_mfma_f32_16x16x32_bf16(h0, l1, d2[0][1], 0, 0, 0);
    d2[1][0] = __builtin_amdgcn_mfma_f32_16x16x32_bf16(h1, l0, d2[1][0], 0, 0, 0);
    d2[1][1] = __builtin_amdgcn_mfma_f32_16x16x32_bf16(h1, l1, d2[1][1], 0, 0, 0);
    d3[0][0] = __builtin_amdgcn_mfma_f32_16x16x32_bf16(l0, h0, d3[0][0], 0, 0, 0);
    d3[0][1] = __builtin_amdgcn_mfma_f32_16x16x32_bf16(l0, h1, d3[0][1], 0, 0, 0);
    d3[1][0] = __builtin_amdgcn_mfma_f32_16x16x32_bf16(l1, h0, d3[1][0], 0, 0, 0);
    d3[1][1] = __builtin_amdgcn_mfma_f32_16x16x32_bf16(l1, h1, d3[1][1], 0, 0, 0);
  }

  // ---- epilogue: combine D1+D2+D3, reduce over 4 waves (LDS, 1 barrier) ----
  __shared__ float mtmp[4 * 1056];    // 16896 B
#pragma unroll
  for (int i = 0; i < 2; ++i)
#pragma unroll
    for (int j = 0; j < 2; ++j) {
      const f32x4 s4 = d1[i][j] + d2[i][j] + d3[i][j];
#pragma unroll
      for (int r = 0; r < 4; ++r) {
        const int row = i * 16 + g * 4 + r;       // m89-verified C/D map
        const int cc  = j * 16 + col;
        mtmp[w * 1056 + row * 33 + cc] = s4[r];
      }
    }
  __syncthreads();

  const int e0 = tid * 4;
  float tmp[4];
#pragma unroll
  for (int u = 0; u < 4; ++u) {
    const int row = (e0 + u) >> 5;
    const int cc  = (e0 + u) & 31;
    float ss = 0.f;
#pragma unroll
    for (int ww = 0; ww < 4; ++ww) ss += mtmp[ww * 1056 + row * 33 + cc];
    tmp[u] = ss;
  }
  float4 o4;
  o4.x = tmp[0]; o4.y = tmp[1]; o4.z = tmp[2]; o4.w = tmp[3];
  *reinterpret_cast<float4*>(part + (size_t)bc * 1024 + e0) = o4;
}

// ---------------------------------------------------------------------------
// Kernel 2: reduce partials over c.  msum[b][e] = sum_c part[b*64+c][e]
// ---------------------------------------------------------------------------
__global__ __launch_bounds__(256) void reduce_c(const float* __restrict__ part,
                                                float* __restrict__ msum) {
  const int bid = blockIdx.x;                // 0..63
  const int b   = bid >> 2;
  const int e   = (bid & 3) * 256 + threadIdx.x;   // 0..1023
  const float* __restrict__ p = part + (size_t)b * 64 * 1024 + e;
  float s0 = 0.f, s1 = 0.f, s2 = 0.f, s3 = 0.f;
#pragma unroll
  for (int c = 0; c < 64; c += 4) {
    s0 += p[(size_t)(c + 0) * 1024];
    s1 += p[(size_t)(c + 1) * 1024];
    s2 += p[(size_t)(c + 2) * 1024];
    s3 += p[(size_t)(c + 3) * 1024];
  }
  msum[b * 1024 + e] = (s0 + s1) + (s2 + s3);
}

// ---------------------------------------------------------------------------
// Kernel 3: softmax over the BATCH axis. Output q-major: mq[b][q*32+k].
// ---------------------------------------------------------------------------
__global__ __launch_bounds__(256) void softmax_b(const float* __restrict__ msum,
                                                 float* __restrict__ mq) {
  const int e = blockIdx.x * 256 + threadIdx.x;    // q*32 + k
  float l[16];
  float mx = -3.4e38f;
#pragma unroll
  for (int b = 0; b < 16; ++b) {
    l[b] = msum[b * 1024 + e];
    mx = fmaxf(mx, l[b]);
  }
  float s = 0.f;
#pragma unroll
  for (int b = 0; b < 16; ++b) {
    l[b] = expf(l[b] - mx);
    s += l[b];
  }
  const float inv = 1.f / s;
#pragma unroll
  for (int b = 0; b < 16; ++b) mq[b * 1024 + e] = l[b] * inv;
}

// ---------------------------------------------------------------------------
// Kernel 4: PV — r19's counted-vmcnt MFMA skeleton + NON-TEMPORAL cache
// policy on the streaming traffic. Working set x+xv+out = 309 MB > 256 MB
// L3: out's write-allocate evicts xv mid-kernel (FETCH=52 of 103 MB).
// Neither stream has reuse -> xv loads use gload_lds aux=nt, out stores use
// __builtin_nontemporal_store (via native f32x4 — HIP float4 class rejected).
// Everything else byte-identical to r19 (validated, absmax 0.0625).
// ---------------------------------------------------------------------------
__global__ __launch_bounds__(256, 4) void pv(const float* __restrict__ xv,
                                             const float* __restrict__ mq,
                                             float* __restrict__ out) {
  const int bc = blockIdx.x;                  // b*64 + c
  const int b  = bc >> 6;
  const float* __restrict__ xvb = xv + (size_t)bc * (Tt * Ss);
  float* __restrict__ ob        = out + (size_t)bc * (Tt * Ss);

  const int tid  = threadIdx.x;
  const int w    = tid >> 6;                  // wave 0..3
  const int lane = tid & 63;
  const int col  = lane & 15;                 // frag column / M row
  const int g    = lane >> 4;                 // k-group (k = 8g..8g+7)

  __shared__ float lds[2][32 * 128];          // 2 x 16384 B

  // ---- M fragments (once per block) — r9/r16-validated ----
  bf16x8 mh[2], ml[2];
#pragma unroll
  for (int qf = 0; qf < 2; ++qf) {
    const float* mp = mq + b * 1024 + (qf * 16 + col) * 32 + g * 8;
    const float4 ma = *reinterpret_cast<const float4*>(mp);
    const float4 mb = *reinterpret_cast<const float4*>(mp + 4);
    uint4 h, l;
    cvt2(ma.x, ma.y, h.x, l.x);
    cvt2(ma.z, ma.w, h.y, l.y);
    cvt2(mb.x, mb.y, h.z, l.z);
    cvt2(mb.z, mb.w, h.w, l.w);
    mh[qf] = __builtin_bit_cast(bf16x8, h);
    ml[qf] = __builtin_bit_cast(bf16x8, l);
  }

  // stage chunk ch (128 floats at off = ch*128) into lds[buf]: 1024 slots =
  // 4 rounds x 256; slot v = row*32 + c4 (linear). Streaming -> nt policy.
  auto stage = [&](int buf, int ch) {
    const int off = ch * 128;
#pragma unroll
    for (int round = 0; round < 4; ++round) {
      const int v   = round * 256 + tid;
      const int row = v >> 5;
      const int c4  = v & 31;
      gload16_nt(xvb + row * Ss + off + c4 * 4,
                 &lds[buf][(round * 256 + w * 64) * 4]);
    }
  };

  stage(0, 0);
  stage(1, 1);

#pragma unroll
  for (int ch = 0; ch < 6; ++ch) {
    // counted wait: chunk ch's loads done; newer loads/stores stay in flight.
    if (ch == 0 || ch == 5) {
      asm volatile("s_waitcnt vmcnt(4)" ::: "memory");
    } else {
      asm volatile("s_waitcnt vmcnt(8)" ::: "memory");
    }
    __builtin_amdgcn_sched_barrier(0);
    __builtin_amdgcn_s_barrier();               // all waves' ch-loads landed

    const float* __restrict__ lbuf = lds[ch & 1];
    const int off = ch * 128;
#pragma unroll
    for (int fi = 0; fi < 2; ++fi) {
      const int sf = 2 * w + fi;                // this wave's frag
      float f8[8];
#pragma unroll
      for (int j = 0; j < 8; ++j)
        f8[j] = lbuf[(8 * g + j) * 128 + sf * 16 + col];
      uint4 hh, lv;
      cvt2(f8[0], f8[1], hh.x, lv.x);
      cvt2(f8[2], f8[3], hh.y, lv.y);
      cvt2(f8[4], f8[5], hh.z, lv.z);
      cvt2(f8[6], f8[7], hh.w, lv.w);
      const bf16x8 vh = __builtin_bit_cast(bf16x8, hh);
      const bf16x8 vl = __builtin_bit_cast(bf16x8, lv);
      const int s0 = off + sf * 16;
#pragma unroll
      for (int qf = 0; qf < 2; ++qf) {
        f32x4 d = {0.f, 0.f, 0.f, 0.f};
        d = __builtin_amdgcn_mfma_f32_16x16x32_bf16(vl, mh[qf], d, 0, 0, 0);
        d = __builtin_amdgcn_mfma_f32_16x16x32_bf16(vh, ml[qf], d, 0, 0, 0);
        d = __builtin_amdgcn_mfma_f32_16x16x32_bf16(vh, mh[qf], d, 0, 0, 0);
        // D[s][q]: lane(col,g) regs = s0+4g..+3 of q-row qf*16+col (r18-valid)
        ntstore4(d, ob + (size_t)(qf * 16 + col) * Ss + s0 + 4 * g);
      }
    }
    asm volatile("s_waitcnt lgkmcnt(0)" ::: "memory");   // LDS reads done
    __builtin_amdgcn_sched_barrier(0);
    __builtin_amdgcn_s_barrier();               // buffer free to restage
    if (ch < 4) stage(ch & 1, ch + 2);          // keep next loads in flight
  }

  // ---- tail frag: s = 768..783, direct from global (wave 3 only) ----
  if (w == 3) {
    float f8[8];
#pragma unroll
    for (int j = 0; j < 8; ++j)
      f8[j] = xvb[(size_t)(8 * g + j) * Ss + 768 + col];
    uint4 hh, lv;
    cvt2(f8[0], f8[1], hh.x, lv.x);
    cvt2(f8[2], f8[3], hh.y, lv.y);
    cvt2(f8[4], f8[5], hh.z, lv.z);
    cvt2(f8[6], f8[7], hh.w, lv.w);
    const bf16x8 vh = __builtin_bit_cast(bf16x8, hh);
    const bf16x8 vl = __builtin_bit_cast(bf16x8, lv);
#pragma unroll
    for (int qf = 0; qf < 2; ++qf) {
      f32x4 d = {0.f, 0.f, 0.f, 0.f};
      d = __builtin_amdgcn_mfma_f32_16x16x32_bf16(vl, mh[qf], d, 0, 0, 0);
      d = __builtin_amdgcn_mfma_f32_16x16x32_bf16(vh, ml[qf], d, 0, 0, 0);
      d = __builtin_amdgcn_mfma_f32_16x16x32_bf16(vh, mh[qf], d, 0, 0, 0);
      ntstore4(d, ob + (size_t)(qf * 16 + col) * Ss + 768 + 4 * g);
    }
  }
}

}  // namespace

extern "C" void kernel_launch(void* const* d_in, const int* in_sizes, int n_in,
                              void* d_out, int out_size, void* d_ws, size_t ws_size,
                              hipStream_t stream) {
  const float* x  = (const float*)d_in[0];
  const float* xv = (const float*)d_in[1];
  float* out = (float*)d_out;

  // workspace (fp32), ~4.2 MiB total:
  float* part = (float*)d_ws;            // 1024 x 1024
  float* msum = part + 1024 * 1024;      // 16 x 1024
  float* mq   = msum + 16 * 1024;        // 16 x 1024 (q-major softmax weights)

  gram_partial<<<dim3(1024), dim3(256), 0, stream>>>(x, part);
  reduce_c<<<dim3(64), dim3(256), 0, stream>>>(part, msum);
  softmax_b<<<dim3(4), dim3(256), 0, stream>>>(msum, mq);
  pv<<<dim3(1024), dim3(256), 0, stream>>>(xv, mq, out);
}

// Round 24
// 73.633 us; speedup vs baseline: 1.1471x; 1.0706x over previous
//
#include <hip/hip_runtime.h>

namespace {

constexpr int Tt = 32;    // frames (t)
constexpr int Ss = 784;   // floats per row (h*w)

using bf16x8 = __attribute__((ext_vector_type(8))) short;
using f32x4  = __attribute__((ext_vector_type(4))) float;

// split fp32 -> hi (truncated bf16) + lo (bf16 of residual); pack 2 per uint
__device__ inline void cvt2(float a, float b, unsigned& h, unsigned& l) {
  const unsigned ha = __float_as_uint(a) >> 16;
  const unsigned hb = __float_as_uint(b) >> 16;
  const float ra = a - __uint_as_float(ha << 16);
  const float rb = b - __uint_as_float(hb << 16);
  const unsigned la = __float_as_uint(ra) >> 16;
  const unsigned lb = __float_as_uint(rb) >> 16;
  h = ha | (hb << 16);
  l = la | (lb << 16);
}

// async global->LDS, 16 B per lane; LDS dest must be wave-uniform base.
__device__ inline void gload16(const float* g, float* l) {
  __builtin_amdgcn_global_load_lds(
      (const __attribute__((address_space(1))) void*)g,
      (__attribute__((address_space(3))) void*)l, 16, 0, 0);
}

// ---------------------------------------------------------------------------
// Kernel 1: per-(b,c) Gram via split-bf16 MFMA, direct-global fragments
// (measured ~15-16 us = its HBM floor).
// ---------------------------------------------------------------------------
__global__ __launch_bounds__(256, 4) void gram_partial(const float* __restrict__ x,
                                                       float* __restrict__ part) {
  const int bc = blockIdx.x;                       // b*64 + c
  const float* __restrict__ xb = x + (size_t)bc * (Tt * Ss);
  const int tid  = threadIdx.x;
  const int w    = tid >> 6;          // wave 0..3
  const int lane = tid & 63;
  const int col  = lane & 15;
  const int g    = lane >> 4;

  f32x4 d1[2][2], d2[2][2], d3[2][2];
#pragma unroll
  for (int i = 0; i < 2; ++i)
#pragma unroll
    for (int j = 0; j < 2; ++j) { d1[i][j] = 0.f; d2[i][j] = 0.f; d3[i][j] = 0.f; }

  const float* __restrict__ pa = xb + (size_t)col * Ss;         // rows 0-15
  const float* __restrict__ pb = xb + (size_t)(16 + col) * Ss;  // rows 16-31

  for (int ks = w; ks < 25; ks += 4) {
    const int s0 = ks * 32 + g * 8;
    uint4 ha = {0u,0u,0u,0u}, la = {0u,0u,0u,0u};
    uint4 hb = {0u,0u,0u,0u}, lb = {0u,0u,0u,0u};
    if (s0 < 784) {
      const float4 a0 = *reinterpret_cast<const float4*>(pa + s0);
      const float4 a1 = *reinterpret_cast<const float4*>(pa + s0 + 4);
      const float4 b0 = *reinterpret_cast<const float4*>(pb + s0);
      const float4 b1 = *reinterpret_cast<const float4*>(pb + s0 + 4);
      cvt2(a0.x, a0.y, ha.x, la.x);
      cvt2(a0.z, a0.w, ha.y, la.y);
      cvt2(a1.x, a1.y, ha.z, la.z);
      cvt2(a1.z, a1.w, ha.w, la.w);
      cvt2(b0.x, b0.y, hb.x, lb.x);
      cvt2(b0.z, b0.w, hb.y, lb.y);
      cvt2(b1.x, b1.y, hb.z, lb.z);
      cvt2(b1.z, b1.w, hb.w, lb.w);
    }
    const bf16x8 h0 = __builtin_bit_cast(bf16x8, ha);
    const bf16x8 l0 = __builtin_bit_cast(bf16x8, la);
    const bf16x8 h1 = __builtin_bit_cast(bf16x8, hb);
    const bf16x8 l1 = __builtin_bit_cast(bf16x8, lb);
    d1[0][0] = __builtin_amdgcn_mfma_f32_16x16x32_bf16(h0, h0, d1[0][0], 0, 0, 0);
    d1[0][1] = __builtin_amdgcn_mfma_f32_16x16x32_bf16(h0, h1, d1[0][1], 0, 0, 0);
    d1[1][0] = __builtin_amdgcn_mfma_f32_16x16x32_bf16(h1, h0, d1[1][0], 0, 0, 0);
    d1[1][1] = __builtin_amdgcn_mfma_f32_16x16x32_bf16(h1, h1, d1[1][1], 0, 0, 0);
    d2[0][0] = __builtin_amdgcn_mfma_f32_16x16x32_bf16(h0, l0, d2[0][0], 0, 0, 0);
    d2[0][1] = __builtin_amdgcn_mfma_f32_16x16x32_bf16(h0, l1, d2[0][1], 0, 0, 0);
    d2[1][0] = __builtin_amdgcn_mfma_f32_16x16x32_bf16(h1, l0, d2[1][0], 0, 0, 0);
    d2[1][1] = __builtin_amdgcn_mfma_f32_16x16x32_bf16(h1, l1, d2[1][1], 0, 0, 0);
    d3[0][0] = __builtin_amdgcn_mfma_f32_16x16x32_bf16(l0, h0, d3[0][0], 0, 0, 0);
    d3[0][1] = __builtin_amdgcn_mfma_f32_16x16x32_bf16(l0, h1, d3[0][1], 0, 0, 0);
    d3[1][0] = __builtin_amdgcn_mfma_f32_16x16x32_bf16(l1, h0, d3[1][0], 0, 0, 0);
    d3[1][1] = __builtin_amdgcn_mfma_f32_16x16x32_bf16(l1, h1, d3[1][1], 0, 0, 0);
  }

  // ---- epilogue: combine D1+D2+D3, reduce over 4 waves (LDS, 1 barrier) ----
  __shared__ float mtmp[4 * 1056];    // 16896 B
#pragma unroll
  for (int i = 0; i < 2; ++i)
#pragma unroll
    for (int j = 0; j < 2; ++j) {
      const f32x4 s4 = d1[i][j] + d2[i][j] + d3[i][j];
#pragma unroll
      for (int r = 0; r < 4; ++r) {
        const int row = i * 16 + g * 4 + r;       // m89-verified C/D map
        const int cc  = j * 16 + col;
        mtmp[w * 1056 + row * 33 + cc] = s4[r];
      }
    }
  __syncthreads();

  const int e0 = tid * 4;
  float tmp[4];
#pragma unroll
  for (int u = 0; u < 4; ++u) {
    const int row = (e0 + u) >> 5;
    const int cc  = (e0 + u) & 31;
    float ss = 0.f;
#pragma unroll
    for (int ww = 0; ww < 4; ++ww) ss += mtmp[ww * 1056 + row * 33 + cc];
    tmp[u] = ss;
  }
  float4 o4;
  o4.x = tmp[0]; o4.y = tmp[1]; o4.z = tmp[2]; o4.w = tmp[3];
  *reinterpret_cast<float4*>(part + (size_t)bc * 1024 + e0) = o4;
}

// ---------------------------------------------------------------------------
// Kernel 2: reduce partials over c.  msum[b][e] = sum_c part[b*64+c][e]
// ---------------------------------------------------------------------------
__global__ __launch_bounds__(256) void reduce_c(const float* __restrict__ part,
                                                float* __restrict__ msum) {
  const int bid = blockIdx.x;                // 0..63
  const int b   = bid >> 2;
  const int e   = (bid & 3) * 256 + threadIdx.x;   // 0..1023
  const float* __restrict__ p = part + (size_t)b * 64 * 1024 + e;
  float s0 = 0.f, s1 = 0.f, s2 = 0.f, s3 = 0.f;
#pragma unroll
  for (int c = 0; c < 64; c += 4) {
    s0 += p[(size_t)(c + 0) * 1024];
    s1 += p[(size_t)(c + 1) * 1024];
    s2 += p[(size_t)(c + 2) * 1024];
    s3 += p[(size_t)(c + 3) * 1024];
  }
  msum[b * 1024 + e] = (s0 + s1) + (s2 + s3);
}

// ---------------------------------------------------------------------------
// Kernel 3: softmax over the BATCH axis. Output q-major: mq[b][q*32+k].
// ---------------------------------------------------------------------------
__global__ __launch_bounds__(256) void softmax_b(const float* __restrict__ msum,
                                                 float* __restrict__ mq) {
  const int e = blockIdx.x * 256 + threadIdx.x;    // q*32 + k
  float l[16];
  float mx = -3.4e38f;
#pragma unroll
  for (int b = 0; b < 16; ++b) {
    l[b] = msum[b * 1024 + e];
    mx = fmaxf(mx, l[b]);
  }
  float s = 0.f;
#pragma unroll
  for (int b = 0; b < 16; ++b) {
    l[b] = expf(l[b] - mx);
    s += l[b];
  }
  const float inv = 1.f / s;
#pragma unroll
  for (int b = 0; b < 16; ++b) mq[b * 1024 + e] = l[b] * inv;
}

// ---------------------------------------------------------------------------
// Kernel 4: PV via split-bf16 MFMA + counted-vmcnt double-buffer (r19 —
// the best measured variant; restored verbatim). 1024 blocks x 256 thr,
// 2 x 16 KB LDS dbuf, counted s_waitcnt vmcnt(8/4) (never 0 mid-loop), raw
// s_barrier, 6 chunks of 128 floats + direct-global 16-float tail (wave 3).
// Validated absmax 0.0625.
// ---------------------------------------------------------------------------
__global__ __launch_bounds__(256, 4) void pv(const float* __restrict__ xv,
                                             const float* __restrict__ mq,
                                             float* __restrict__ out) {
  const int bc = blockIdx.x;                  // b*64 + c
  const int b  = bc >> 6;
  const float* __restrict__ xvb = xv + (size_t)bc * (Tt * Ss);
  float* __restrict__ ob        = out + (size_t)bc * (Tt * Ss);

  const int tid  = threadIdx.x;
  const int w    = tid >> 6;                  // wave 0..3
  const int lane = tid & 63;
  const int col  = lane & 15;                 // frag column / M row
  const int g    = lane >> 4;                 // k-group (k = 8g..8g+7)

  __shared__ float lds[2][32 * 128];          // 2 x 16384 B

  // ---- M fragments (once per block) — r9/r16-validated ----
  bf16x8 mh[2], ml[2];
#pragma unroll
  for (int qf = 0; qf < 2; ++qf) {
    const float* mp = mq + b * 1024 + (qf * 16 + col) * 32 + g * 8;
    const float4 ma = *reinterpret_cast<const float4*>(mp);
    const float4 mb = *reinterpret_cast<const float4*>(mp + 4);
    uint4 h, l;
    cvt2(ma.x, ma.y, h.x, l.x);
    cvt2(ma.z, ma.w, h.y, l.y);
    cvt2(mb.x, mb.y, h.z, l.z);
    cvt2(mb.z, mb.w, h.w, l.w);
    mh[qf] = __builtin_bit_cast(bf16x8, h);
    ml[qf] = __builtin_bit_cast(bf16x8, l);
  }

  // stage chunk ch (128 floats at off = ch*128) into lds[buf]: 1024 slots =
  // 4 rounds x 256; slot v = row*32 + c4 (linear).
  auto stage = [&](int buf, int ch) {
    const int off = ch * 128;
#pragma unroll
    for (int round = 0; round < 4; ++round) {
      const int v   = round * 256 + tid;
      const int row = v >> 5;
      const int c4  = v & 31;
      gload16(xvb + row * Ss + off + c4 * 4,
              &lds[buf][(round * 256 + w * 64) * 4]);
    }
  };

  stage(0, 0);
  stage(1, 1);

#pragma unroll
  for (int ch = 0; ch < 6; ++ch) {
    // counted wait: chunk ch's loads done; newer loads/stores stay in flight.
    if (ch == 0 || ch == 5) {
      asm volatile("s_waitcnt vmcnt(4)" ::: "memory");
    } else {
      asm volatile("s_waitcnt vmcnt(8)" ::: "memory");
    }
    __builtin_amdgcn_sched_barrier(0);
    __builtin_amdgcn_s_barrier();               // all waves' ch-loads landed

    const float* __restrict__ lbuf = lds[ch & 1];
    const int off = ch * 128;
#pragma unroll
    for (int fi = 0; fi < 2; ++fi) {
      const int sf = 2 * w + fi;                // this wave's frag
      float f8[8];
#pragma unroll
      for (int j = 0; j < 8; ++j)
        f8[j] = lbuf[(8 * g + j) * 128 + sf * 16 + col];
      uint4 hh, lv;
      cvt2(f8[0], f8[1], hh.x, lv.x);
      cvt2(f8[2], f8[3], hh.y, lv.y);
      cvt2(f8[4], f8[5], hh.z, lv.z);
      cvt2(f8[6], f8[7], hh.w, lv.w);
      const bf16x8 vh = __builtin_bit_cast(bf16x8, hh);
      const bf16x8 vl = __builtin_bit_cast(bf16x8, lv);
      const int s0 = off + sf * 16;
#pragma unroll
      for (int qf = 0; qf < 2; ++qf) {
        f32x4 d = {0.f, 0.f, 0.f, 0.f};
        d = __builtin_amdgcn_mfma_f32_16x16x32_bf16(vl, mh[qf], d, 0, 0, 0);
        d = __builtin_amdgcn_mfma_f32_16x16x32_bf16(vh, ml[qf], d, 0, 0, 0);
        d = __builtin_amdgcn_mfma_f32_16x16x32_bf16(vh, mh[qf], d, 0, 0, 0);
        // D[s][q]: lane(col,g) regs = s0+4g..+3 of q-row qf*16+col (r18-valid)
        float4 o4;
        o4.x = d[0]; o4.y = d[1]; o4.z = d[2]; o4.w = d[3];
        *reinterpret_cast<float4*>(ob + (size_t)(qf * 16 + col) * Ss + s0 + 4 * g) = o4;
      }
    }
    asm volatile("s_waitcnt lgkmcnt(0)" ::: "memory");   // LDS reads done
    __builtin_amdgcn_sched_barrier(0);
    __builtin_amdgcn_s_barrier();               // buffer free to restage
    if (ch < 4) stage(ch & 1, ch + 2);          // keep next loads in flight
  }

  // ---- tail frag: s = 768..783, direct from global (wave 3 only) ----
  if (w == 3) {
    float f8[8];
#pragma unroll
    for (int j = 0; j < 8; ++j)
      f8[j] = xvb[(size_t)(8 * g + j) * Ss + 768 + col];
    uint4 hh, lv;
    cvt2(f8[0], f8[1], hh.x, lv.x);
    cvt2(f8[2], f8[3], hh.y, lv.y);
    cvt2(f8[4], f8[5], hh.z, lv.z);
    cvt2(f8[6], f8[7], hh.w, lv.w);
    const bf16x8 vh = __builtin_bit_cast(bf16x8, hh);
    const bf16x8 vl = __builtin_bit_cast(bf16x8, lv);
#pragma unroll
    for (int qf = 0; qf < 2; ++qf) {
      f32x4 d = {0.f, 0.f, 0.f, 0.f};
      d = __builtin_amdgcn_mfma_f32_16x16x32_bf16(vl, mh[qf], d, 0, 0, 0);
      d = __builtin_amdgcn_mfma_f32_16x16x32_bf16(vh, ml[qf], d, 0, 0, 0);
      d = __builtin_amdgcn_mfma_f32_16x16x32_bf16(vh, mh[qf], d, 0, 0, 0);
      float4 o4;
      o4.x = d[0]; o4.y = d[1]; o4.z = d[2]; o4.w = d[3];
      *reinterpret_cast<float4*>(ob + (size_t)(qf * 16 + col) * Ss + 768 + 4 * g) = o4;
    }
  }
}

}  // namespace

extern "C" void kernel_launch(void* const* d_in, const int* in_sizes, int n_in,
                              void* d_out, int out_size, void* d_ws, size_t ws_size,
                              hipStream_t stream) {
  const float* x  = (const float*)d_in[0];
  const float* xv = (const float*)d_in[1];
  float* out = (float*)d_out;

  // workspace (fp32), ~4.2 MiB total:
  float* part = (float*)d_ws;            // 1024 x 1024
  float* msum = part + 1024 * 1024;      // 16 x 1024
  float* mq   = msum + 16 * 1024;        // 16 x 1024 (q-major softmax weights)

  gram_partial<<<dim3(1024), dim3(256), 0, stream>>>(x, part);
  reduce_c<<<dim3(64), dim3(256), 0, stream>>>(part, msum);
  softmax_b<<<dim3(4), dim3(256), 0, stream>>>(msum, mq);
  pv<<<dim3(1024), dim3(256), 0, stream>>>(xv, mq, out);
}